// Round 3
// baseline (324.747 us; speedup 1.0000x reference)
//
#include <hip/hip_runtime.h>
#include <stdint.h>

// BitLinear: y = (int8(x) @ unpack2bit(Wp)^T) * amax/(127*ws) + bias
// M=16384 tokens, K=2048, N=2048. Integer GEMM, mfma_i32_32x32x32_i8.
// R5: B path moved out of LDS -> direct global->VGPR loads (W is L2-resident,
//     4MB; each lane loads its own 16B fragment, no cross-lane need). Removes
//     B LDS writes+reads (256KB -> 160KB LDS traffic per tile per CU, below
//     the ~2330cyc MFMA floor) and B's bank conflicts, and halves barriers
//     (2/tile: only A staging needs them). B double-buffered in two named
//     register sets (tile loop unrolled x2, static indexing). Counted-vmcnt
//     schedule re-derived: per-tile issues [A0'(2),B'0(4) | B'1(4) | A1'(2)],
//     waits ph1=12, ph2=10(+BAR), ph4=10(+BAR); steady entry queue = 10;
//     prologue shaped as a tile body; tail drains 6 -> 0.
//     A keeps XOR-swizzled LDS (slot = chunk ^ (row&7)) via pre-swizzled
//     global source + global_load_lds; XCD-aware block swizzle kept.

typedef __attribute__((ext_vector_type(4)))  int int4v;
typedef __attribute__((ext_vector_type(16))) int int16v;

#define GLOBAL_AS __attribute__((address_space(1)))
#define LDS_AS    __attribute__((address_space(3)))

static constexpr int MK = 2048;   // K (inner dim)
static constexpr int NN = 2048;   // out features
static constexpr int MM = 16384;  // tokens

// ---------------- activation quant: one block per token row (unchanged) ----
__global__ void quant_kernel(const float* __restrict__ x,
                             const float* __restrict__ wscale,
                             signed char* __restrict__ xq,
                             float* __restrict__ rf) {
    const int m = blockIdx.x;
    const int t = threadIdx.x;
    const float4* xr = (const float4*)(x + (size_t)m * MK);  // 512 float4/row
    float4 v0 = xr[t];
    float4 v1 = xr[t + 256];
    float amax = fmaxf(fmaxf(fabsf(v0.x), fabsf(v0.y)),
                       fmaxf(fabsf(v0.z), fabsf(v0.w)));
    amax = fmaxf(amax, fmaxf(fmaxf(fabsf(v1.x), fabsf(v1.y)),
                             fmaxf(fabsf(v1.z), fabsf(v1.w))));
    #pragma unroll
    for (int off = 32; off >= 1; off >>= 1)
        amax = fmaxf(amax, __shfl_xor(amax, off));
    __shared__ float smax[4];
    if ((t & 63) == 0) smax[t >> 6] = amax;
    __syncthreads();
    float a0 = fmaxf(fmaxf(smax[0], smax[1]), fmaxf(smax[2], smax[3]));
    a0 = fmaxf(a0, 1e-5f);
    const float scale = 127.0f / a0;
    if (t == 0) rf[m] = a0 / (127.0f * wscale[0]);

    auto q = [&](float f) -> int {
        float r = rintf(f * scale);        // round-half-to-even
        r = fminf(fmaxf(r, -128.0f), 127.0f);
        return (int)r;
    };
    int p0 = (q(v0.x) & 255) | ((q(v0.y) & 255) << 8) |
             ((q(v0.z) & 255) << 16) | ((q(v0.w) & 255) << 24);
    int p1 = (q(v1.x) & 255) | ((q(v1.y) & 255) << 8) |
             ((q(v1.z) & 255) << 16) | ((q(v1.w) & 255) << 24);
    int* xqr = (int*)(xq + (size_t)m * MK);
    xqr[t]       = p0;
    xqr[t + 256] = p1;
}

// ---------------- weight unpack (unchanged) --------------------------------
__global__ void unpack_kernel(const int* __restrict__ packed,
                              signed char* __restrict__ W) {
    const int idx = blockIdx.x * 256 + threadIdx.x;   // 0 .. 512*512
    const int r  = idx >> 9;        // packed row
    const int kq = idx & 511;       // k/4
    const int4 p = ((const int4*)packed)[idx];        // 4 consecutive k
    int* Wi = (int*)W;              // 512 ints per W row
    #pragma unroll
    for (int i = 0; i < 4; i++) {
        const int sh = 2 * i;
        int b0 = ((((p.x >> sh) & 3) - 1) & 255);
        int b1 = ((((p.y >> sh) & 3) - 1) & 255);
        int b2 = ((((p.z >> sh) & 3) - 1) & 255);
        int b3 = ((((p.w >> sh) & 3) - 1) & 255);
        Wi[(i * 512 + r) * 512 + kq] = b0 | (b1 << 8) | (b2 << 16) | (b3 << 24);
    }
}

// ---------------- int8 GEMM: 256x256 tile, A-in-LDS, B-in-regs -------------
// LDS (64 KiB): A only, buf{0,1} x 32 KiB. Stage-half h (16 KiB) holds 128
// rows linearly (128 B/row); logical 16B chunk c of in-half row rw sits at
// slot c ^ (rw&7). A halves stripe at 64 rows (h == MH quadrant).
#define WAITV(N) asm volatile("s_waitcnt vmcnt(" #N ")" ::: "memory")
#define BAR() do { __builtin_amdgcn_s_barrier(); \
                   __builtin_amdgcn_sched_barrier(0); } while (0)

__device__ __forceinline__ void stage_half(const signed char* __restrict__ src,
                                           int row0, int k0, int h,
                                           unsigned char* plane,
                                           int wave, int lane) {
    // lane writes LDS at (wave*2+j)*1024 + lane*16 -> in-half row rw, slot
    // lane&7. Fetch the logical chunk belonging in that slot:
    // c = (lane&7) ^ (rw&7), and rw&7 == lane>>3 for all groups.
    const int csrc = (((lane & 7) ^ (lane >> 3)) << 4);
    #pragma unroll
    for (int j = 0; j < 2; ++j) {
        const int rw = wave * 16 + j * 8 + (lane >> 3);          // 0..127
        const int r  = (rw & 63) + h * 64 + ((rw >> 6) << 7);    // tile row
        const signed char* ga = src + (size_t)(row0 + r) * MK + k0 + csrc;
        __builtin_amdgcn_global_load_lds((const GLOBAL_AS void*)ga,
            (LDS_AS void*)(plane + (h << 14) + (wave * 2 + j) * 1024),
            16, 0, 0);
    }
}

#define RD_A(MH, cb)                                                           \
  _Pragma("unroll")                                                           \
  for (int mt = 0; mt < 2; ++mt)                                              \
    _Pragma("unroll")                                                         \
    for (int ks = 0; ks < 4; ++ks)                                            \
      a[mt][ks] = *(const int4v*)(shp + (cb) + (MH)*16384 + arow + mt*4096    \
                                  + cbyte[ks]);

// B fragment loads: lane (ar,hl) reads W row n0+wn*64+NH*32+ar, chunk 2ks+hl.
#define LOADB(B, NH, k1)                                                       \
  _Pragma("unroll")                                                           \
  for (int ks = 0; ks < 4; ++ks)                                              \
    B[NH][ks] = *(const int4v*)(bptr + (size_t)(NH) * 32 * MK + (k1) + ks*32);

#define MFM(MH, NH, breg)                                                      \
  do {                                                                         \
    __builtin_amdgcn_s_setprio(1);                                             \
    _Pragma("unroll")                                                          \
    for (int mt = 0; mt < 2; ++mt)                                             \
      _Pragma("unroll")                                                        \
      for (int ks = 0; ks < 4; ++ks)                                           \
        acc[(MH)*2+mt][NH] = __builtin_amdgcn_mfma_i32_32x32x32_i8(            \
            a[mt][ks], breg[ks], acc[(MH)*2+mt][NH], 0, 0, 0);                 \
    __builtin_amdgcn_s_setprio(0);                                             \
  } while (0)

// One K-tile: cb = current A buf, nb = next A buf, k1 = next tile's k0.
// BC = current B reg set, BN = next B reg set (loaded for t+1).
#define BODY(cb, nb, k1)                                                       \
  do {                                                                         \
    /* ph1 */                                                                  \
    RD_A(0, cb);                                                               \
    stage_half(xq, m0, (k1), 0, shp + (nb), wave, lane);                       \
    LOADB(BN, 0, (k1));                                                        \
    WAITV(12); __builtin_amdgcn_sched_barrier(0);                              \
    MFM(0, 0, BC[0]);                                                          \
    /* ph2 */                                                                  \
    LOADB(BN, 1, (k1));                                                        \
    WAITV(10); BAR();                                                          \
    MFM(0, 1, BC[1]);                                                          \
    /* ph3 */                                                                  \
    RD_A(1, cb);                                                               \
    stage_half(xq, m0, (k1), 1, shp + (nb), wave, lane);                       \
    MFM(1, 0, BC[0]);                                                          \
    /* ph4 */                                                                  \
    WAITV(10); BAR();                                                          \
    MFM(1, 1, BC[1]);                                                          \
  } while (0)

__global__ void __launch_bounds__(512, 2)
gemm_kernel(const signed char* __restrict__ xq,   // [M][K]
            const signed char* __restrict__ W,    // [N][K]
            const float* __restrict__ rf,         // [M]
            const float* __restrict__ bias,       // [N]
            float* __restrict__ out) {            // [M][N]
    __shared__ __attribute__((aligned(16))) unsigned char sh[65536];
    unsigned char* shp = sh;

    const int tid  = threadIdx.x;
    const int wave = tid >> 6;
    const int lane = tid & 63;
    const int wm = wave >> 2;          // 0..1: wave's 128-row M band
    const int wn = wave & 3;           // 0..3: wave's 64-col N band

    // XCD-aware swizzle: 512 blocks = 8 XCDs x 64 contiguous chunks
    const int bs = ((blockIdx.x & 7) << 6) | (blockIdx.x >> 3);
    const int m0 = (bs >> 3) << 8;     // 64 M-tiles
    const int n0 = (bs & 7) << 8;      // 8  N-tiles

    // 32x32x32 fragment addressing: lane holds row ar = lane&31,
    // K-chunk (ks*2 + hl) of 16B, hl = lane>>5. Swizzled slot = c ^ (ar&7).
    const int ar = lane & 31, hl = lane >> 5;
    int cbyte[4];
    #pragma unroll
    for (int ks = 0; ks < 4; ++ks)
        cbyte[ks] = ((((ks << 1) | hl) ^ (ar & 7)) << 4);
    const int arow = (wm * 64 + ar) * 128;          // + MH*16384 + mt*4096

    // per-lane B base: row n0 + wn*64 + ar, byte offset hl*16
    const signed char* bptr = W + (size_t)(n0 + wn * 64 + ar) * MK + hl * 16;

    int4v a[2][4];
    int4v bX[2][4], bY[2][4];          // B double-buffer (named sets)
    int16v acc[4][2] = {};             // [MH*2+mt][NH]

    // prologue, shaped like a tile body: issue [A0(2), B0(4), B1(4), A1(2)],
    // drain A0 -> steady-state entry queue = [B0(4), B1(4), A1(2)] = 10.
    stage_half(xq, m0, 0, 0, shp, wave, lane);
    { LOADB(bX, 0, 0); }
    { LOADB(bX, 1, 0); }
    stage_half(xq, m0, 0, 1, shp, wave, lane);
    WAITV(10); BAR();

    #pragma unroll 1
    for (int tp = 0; tp < 7; ++tp) {
        const int k1a = (2 * tp + 1) << 7;
        const int k1b = (2 * tp + 2) << 7;
        #define BC bX
        #define BN bY
        BODY(0, 32768, k1a);           // even tile: A in buf0, B in bX
        #undef BC
        #undef BN
        #define BC bY
        #define BN bX
        BODY(32768, 0, k1b);           // odd tile: A in buf1, B in bY
        #undef BC
        #undef BN
    }
    {   // tile 14 (even, buf0, bX), prefetch tile 15 into buf1/bY
        #define BC bX
        #define BN bY
        BODY(0, 32768, 15 << 7);
        #undef BC
        #undef BN
    }
    {   // tail tile 15 (buf1, bY): no prefetch, drain 6 -> 0
        RD_A(0, 32768);
        WAITV(6); __builtin_amdgcn_sched_barrier(0);
        MFM(0, 0, bY[0]);
        WAITV(0); BAR();
        MFM(0, 1, bY[1]);
        RD_A(1, 32768);
        MFM(1, 0, bY[0]);
        MFM(1, 1, bY[1]);
    }

    // epilogue: 32x32 C/D map col=lane&31, row=(reg&3)+8*(reg>>2)+4*(lane>>5)
    const int nb0 = n0 + wn * 64 + ar;
    const float bva = bias[nb0];
    const float bvb = bias[nb0 + 32];
    #pragma unroll
    for (int MH = 0; MH < 2; ++MH) {
        #pragma unroll
        for (int mt = 0; mt < 2; ++mt) {
            const int mbase = m0 + wm * 128 + MH * 64 + mt * 32 + hl * 4;
            #pragma unroll
            for (int q = 0; q < 4; ++q) {
                #pragma unroll
                for (int rr = 0; rr < 4; ++rr) {
                    const int m = mbase + q * 8 + rr;
                    const float frm = rf[m];
                    float* orow = out + (size_t)m * NN;
                    orow[nb0]      = (float)acc[MH*2+mt][0][q*4+rr] * frm + bva;
                    orow[nb0 + 32] = (float)acc[MH*2+mt][1][q*4+rr] * frm + bvb;
                }
            }
        }
    }
}

extern "C" void kernel_launch(void* const* d_in, const int* in_sizes, int n_in,
                              void* d_out, int out_size, void* d_ws, size_t ws_size,
                              hipStream_t stream) {
    const float* x      = (const float*)d_in[0];
    const int*   packed = (const int*)d_in[1];
    const float* wscale = (const float*)d_in[2];
    const float* bias   = (const float*)d_in[3];
    float* out = (float*)d_out;

    // workspace: xq [16384*2048] i8 | W [2048*2048] i8 | rf [16384] f32
    signed char* xq = (signed char*)d_ws;
    signed char* W  = xq + (size_t)MM * MK;
    float*       rf = (float*)(W + (size_t)NN * MK);

    quant_kernel<<<MM, 256, 0, stream>>>(x, wscale, xq, rf);
    unpack_kernel<<<(512 * 512) / 256, 256, 0, stream>>>(packed, W);
    gemm_kernel<<<dim3(512), 512, 0, stream>>>(xq, W, rf, bias, out);
}